// Round 13
// baseline (552.212 us; speedup 1.0000x reference)
//
#include <hip/hip_runtime.h>
#include <hip/hip_bf16.h>

typedef float f32x4 __attribute__((ext_vector_type(4)));
typedef short bf16x8 __attribute__((ext_vector_type(8)));

#define NB 50000
#define NK 32
#define NH 128
#define NL 64

// LDS-only barrier: waits LDS ops, leaves global (vmcnt) prefetch in flight.
#define LBAR() do { asm volatile("s_waitcnt lgkmcnt(0)" ::: "memory"); \
                    __builtin_amdgcn_s_barrier(); \
                    asm volatile("" ::: "memory"); } while (0)

static __device__ __forceinline__ unsigned short f2bf(float f) {
    unsigned int u = __float_as_uint(f);
    u += 0x7fffu + ((u >> 16) & 1u);
    return (unsigned short)(u >> 16);
}
static __device__ __forceinline__ float bf2f(unsigned short u) {
    return __uint_as_float(((unsigned int)u) << 16);
}
static __device__ __forceinline__ float bflo(unsigned int u) { return __uint_as_float(u << 16); }
static __device__ __forceinline__ float bfhi(unsigned int u) { return __uint_as_float(u & 0xffff0000u); }

__global__ void kl_zero_kernel(float* out) {
    if (threadIdx.x == 0 && blockIdx.x == 0) out[(size_t)NB * NH] = 0.0f;
}

// ---------------- K0: Wvo = Wv@Wo (f32, ws), bvo = b_v@Wo + b_o ----------------
__global__ void __launch_bounds__(256) wvo_kernel(const float* __restrict__ W_v,
                                                  const float* __restrict__ W_o,
                                                  const float* __restrict__ b_v,
                                                  const float* __restrict__ b_o,
                                                  float* __restrict__ wvo_ws,
                                                  float* __restrict__ bvo_ws)
{
    const int t = threadIdx.x;
    for (int e = t; e < 64 * 128; e += 256) {
        int d = e >> 7, h = e & 127;
        float s = 0.f;
#pragma unroll 8
        for (int c = 0; c < 64; ++c) s += W_v[d * 64 + c] * W_o[c * 128 + h];
        wvo_ws[e] = s;
    }
    if (t < 128) {
        float s = b_o[t];
#pragma unroll 8
        for (int c = 0; c < 64; ++c) s += b_v[c] * W_o[c * 128 + t];
        bvo_ws[t] = s;
    }
}

// ---------------- K1: qk = (self@Wq + b_q) @ Wk^T   (f32 out to ws) ----------------
__global__ void __launch_bounds__(256) qk_kernel(const float* __restrict__ self_feat,
                                                 const float* __restrict__ W_q,
                                                 const float* __restrict__ b_q,
                                                 const float* __restrict__ W_k,
                                                 float* __restrict__ qk_ws)
{
    __shared__ __align__(16) unsigned short A[32 * 128];
    __shared__ __align__(16) unsigned short ZQ[32 * 64];
    const int t = threadIdx.x, w = t >> 6, l = t & 63, g = l >> 4, li = l & 15;

    bf16x8 Bq[4];
#pragma unroll
    for (int s = 0; s < 4; ++s) {
        int k0 = 32 * s + 8 * g, c = li + 16 * w;
        bf16x8 f;
#pragma unroll
        for (int j = 0; j < 8; ++j) f[j] = (short)f2bf(W_q[(k0 + j) * 64 + c]);
        Bq[s] = f;
    }
    bf16x8 Bk[2];
#pragma unroll
    for (int s = 0; s < 2; ++s) {
        int k0 = 32 * s + 8 * g, d = li + 16 * w;
        bf16x8 f;
#pragma unroll
        for (int j = 0; j < 8; ++j) f[j] = (short)f2bf(W_k[d * 64 + k0 + j]);
        Bk[s] = f;
    }
    const float bq = b_q[li + 16 * w];
    const int n0 = blockIdx.x * 32;

    {
        int row = t >> 3, c0 = (t & 7) * 16;
        float x[16];
        if (n0 + row < NB) {
            const float* src = self_feat + (size_t)(n0 + row) * NH + c0;
#pragma unroll
            for (int i = 0; i < 4; ++i) {
                float4 v4 = ((const float4*)src)[i];
                x[4 * i] = v4.x; x[4 * i + 1] = v4.y; x[4 * i + 2] = v4.z; x[4 * i + 3] = v4.w;
            }
        } else {
#pragma unroll
            for (int i = 0; i < 16; ++i) x[i] = 0.f;
        }
        alignas(16) unsigned short yb[16];
#pragma unroll
        for (int i = 0; i < 16; ++i) yb[i] = f2bf(x[i]);
        int boff = row * 256 + c0 * 2;
        *(int4*)((char*)A + ((boff) ^ ((row & 7) << 4))) = *(int4*)&yb[0];
        *(int4*)((char*)A + ((boff + 16) ^ ((row & 7) << 4))) = *(int4*)&yb[8];
    }
    __syncthreads();

    const f32x4 zero4 = {0.f, 0.f, 0.f, 0.f};
    f32x4 acc[2] = {zero4, zero4};
#pragma unroll
    for (int s = 0; s < 4; ++s) {
        bf16x8 A0 = *(const bf16x8*)((const char*)A + ((li * 256 + s * 64 + g * 16) ^ ((li & 7) << 4)));
        bf16x8 A1 = *(const bf16x8*)((const char*)A + (((16 + li) * 256 + s * 64 + g * 16) ^ ((li & 7) << 4)));
        acc[0] = __builtin_amdgcn_mfma_f32_16x16x32_bf16(A0, Bq[s], acc[0], 0, 0, 0);
        acc[1] = __builtin_amdgcn_mfma_f32_16x16x32_bf16(A1, Bq[s], acc[1], 0, 0, 0);
    }
#pragma unroll
    for (int mt = 0; mt < 2; ++mt)
#pragma unroll
        for (int r = 0; r < 4; ++r) {
            int row = 16 * mt + 4 * g + r, c = li + 16 * w;
            *(unsigned short*)((char*)ZQ + ((row * 128 + c * 2) ^ ((row & 7) << 4))) = f2bf(acc[mt][r] + bq);
        }
    __syncthreads();

    f32x4 acc2[2] = {zero4, zero4};
#pragma unroll
    for (int s = 0; s < 2; ++s) {
        bf16x8 A0 = *(const bf16x8*)((const char*)ZQ + ((li * 128 + s * 64 + g * 16) ^ ((li & 7) << 4)));
        bf16x8 A1 = *(const bf16x8*)((const char*)ZQ + (((16 + li) * 128 + s * 64 + g * 16) ^ (((16 + li) & 7) << 4)));
        acc2[0] = __builtin_amdgcn_mfma_f32_16x16x32_bf16(A0, Bk[s], acc2[0], 0, 0, 0);
        acc2[1] = __builtin_amdgcn_mfma_f32_16x16x32_bf16(A1, Bk[s], acc2[1], 0, 0, 0);
    }
#pragma unroll
    for (int mt = 0; mt < 2; ++mt)
#pragma unroll
        for (int r = 0; r < 4; ++r) {
            int row = 16 * mt + 4 * g + r;
            if (n0 + row < NB)
                qk_ws[(size_t)(n0 + row) * 64 + li + 16 * w] = acc2[mt][r];
        }
}

// ---- K2: fused main — wave-pair per node, 2 streams/block, 2 barriers/node ----
// Wave w: stream st=w>>1, pair-half p=w&1 (rows 16p..16p+15 of the node).
// M=16 MFMA: A-frag lane li owns neighbor row 16p+li; C-layout rows 4g+r, cols li+16nt.
__global__ void __launch_bounds__(256) fz13_kernel(
    const float* __restrict__ neighbor_feat, const float* __restrict__ trust_mask,
    const float* __restrict__ eps_g,
    const float* __restrict__ pre_g, const float* __restrict__ pre_b,
    const float* __restrict__ W_mu, const float* __restrict__ b_mu,
    const float* __restrict__ W_lv, const float* __restrict__ b_lv,
    const float* __restrict__ post_g, const float* __restrict__ post_b,
    const float* __restrict__ qk_ws, const float* __restrict__ wvo_ws,
    const float* __restrict__ bvo_ws,
    float* __restrict__ out)
{
    __shared__ uint4 WmlB[8 * 4 * 64];        // 32KB: [nt][s][lane] (nt<4 = W_mu, else W_lv)
    __shared__ unsigned int WvoP[64 * 64];    // 16KB: [c][h] packs col h (lo) / h+64 (hi)
    __shared__ float2 s_pgb[128];             // 1KB
    __shared__ float logit_l[2][32];          // per-stream logits
    __shared__ float zbar_l[2][2][64];        // per-stream per-half zbar partials
    __shared__ float klw[4];

    const int t = threadIdx.x, w = t >> 6, l = t & 63, g = l >> 4, li = l & 15;
    const int st = w >> 1, p = w & 1;

    if (t < 128) s_pgb[t] = make_float2(pre_g[t], pre_b[t]);
    for (int e = t; e < 2048; e += 256) {   // WmlB
        int nt = e >> 8, s = (e >> 6) & 3, ln = e & 63;
        const float* src = (nt < 4) ? W_mu : W_lv;
        int gg = ln >> 4, ll = ln & 15, c = ll + 16 * (nt & 3);
        unsigned int pk[4];
#pragma unroll
        for (int jp = 0; jp < 4; ++jp) {
            int k = 32 * s + 8 * gg + 2 * jp;
            pk[jp] = (unsigned)f2bf(src[k * 64 + c]) | ((unsigned)f2bf(src[(k + 1) * 64 + c]) << 16);
        }
        WmlB[e] = make_uint4(pk[0], pk[1], pk[2], pk[3]);
    }
    for (int e = t; e < 4096; e += 256) {   // WvoP
        int c = e >> 6, h = e & 63;
        WvoP[e] = (unsigned)f2bf(wvo_ws[c * 128 + h]) | ((unsigned)f2bf(wvo_ws[c * 128 + h + 64]) << 16);
    }
    float bmu4[4], blv4[4], pg4[4], pb4[4];
#pragma unroll
    for (int nt = 0; nt < 4; ++nt) {
        int c = li + 16 * nt;
        bmu4[nt] = b_mu[c]; blv4[nt] = b_lv[c]; pg4[nt] = post_g[c]; pb4[nt] = post_b[c];
    }
    const float bvo_r = bvo_ws[64 * p + l];
    __syncthreads();

    int node = blockIdx.x * 8 + 4 * st;   // stream st handles nodes node..node+3
    const int rowbase = 16 * p;

    f32x4 xr[4][2];      // row 16p+li, cols 32s+8g+4h+{0..3}
    float epr[16];       // eps[row 16p+4g+r][col li+16nt]  (idx nt*4+r)
    float qk4[4], trl[4];
    {   // prologue prefetch
        const float* src = neighbor_feat + ((size_t)node * NK + rowbase + li) * NH + 8 * g;
#pragma unroll
        for (int s = 0; s < 4; ++s)
#pragma unroll
            for (int h = 0; h < 2; ++h)
                xr[s][h] = *(const f32x4*)(src + 32 * s + 4 * h);
        const float* ep = eps_g + ((size_t)node * NK + rowbase) * NL;
#pragma unroll
        for (int nt = 0; nt < 4; ++nt)
#pragma unroll
            for (int r = 0; r < 4; ++r)
                epr[nt * 4 + r] = ep[(4 * g + r) * NL + li + 16 * nt];
#pragma unroll
        for (int nt = 0; nt < 4; ++nt) qk4[nt] = qk_ws[(size_t)node * 64 + li + 16 * nt];
#pragma unroll
        for (int r = 0; r < 4; ++r) trl[r] = trust_mask[(size_t)node * NK + rowbase + 4 * g + r];
    }

    float kl_acc = 0.f;
    const f32x4 zero4 = {0.f, 0.f, 0.f, 0.f};

#pragma unroll 1
    for (int i = 0; i < 4; ++i) {
        const int nxt = (i < 3) ? node + 1 : node;

        // ---- P0: pre-LN in registers (row stats across g via shfl 16/32) ----
        float s1 = 0.f;
#pragma unroll
        for (int s = 0; s < 4; ++s)
#pragma unroll
            for (int h = 0; h < 2; ++h) {
                f32x4 v = xr[s][h];
                s1 += v[0] + v[1] + v[2] + v[3];
            }
        s1 += __shfl_xor(s1, 16); s1 += __shfl_xor(s1, 32);
        float mean = s1 * (1.f / 128.f);
        float s2 = 0.f;
#pragma unroll
        for (int s = 0; s < 4; ++s)
#pragma unroll
            for (int h = 0; h < 2; ++h)
#pragma unroll
                for (int c = 0; c < 4; ++c) { float d = xr[s][h][c] - mean; s2 += d * d; }
        s2 += __shfl_xor(s2, 16); s2 += __shfl_xor(s2, 32);
        float inv = rsqrtf(s2 * (1.f / 128.f) + 1e-5f);
        bf16x8 a[4];
#pragma unroll
        for (int s = 0; s < 4; ++s) {
            const float2* gbp = &s_pgb[32 * s + 8 * g];
#pragma unroll
            for (int h = 0; h < 2; ++h)
#pragma unroll
                for (int c = 0; c < 4; ++c) {
                    int j = 4 * h + c;
                    float2 gb = gbp[j];
                    a[s][j] = (short)f2bf((xr[s][h][c] - mean) * inv * gb.x + gb.y);
                }
        }
        {   // reissue nbr for next node
            const float* src = neighbor_feat + ((size_t)nxt * NK + rowbase + li) * NH + 8 * g;
#pragma unroll
            for (int s = 0; s < 4; ++s)
#pragma unroll
                for (int h = 0; h < 2; ++h)
                    xr[s][h] = *(const f32x4*)(src + 32 * s + 4 * h);
        }

        // ---- P1: GEMM1: 16 rows x 128 cols [mu|lv], all in this wave ----
        f32x4 acc[8];
#pragma unroll
        for (int nt = 0; nt < 8; ++nt) acc[nt] = zero4;
#pragma unroll
        for (int s = 0; s < 4; ++s)
#pragma unroll
            for (int nt = 0; nt < 8; ++nt) {
                bf16x8 fb = *(const bf16x8*)&WmlB[(nt * 4 + s) * 64 + l];
                acc[nt] = __builtin_amdgcn_mfma_f32_16x16x32_bf16(a[s], fb, acc[nt], 0, 0, 0);
            }

        // ---- P2: reparam + KL (lane-local) ----
        float zn[4][4];
#pragma unroll
        for (int nt = 0; nt < 4; ++nt)
#pragma unroll
            for (int r = 0; r < 4; ++r) {
                float mu = acc[nt][r] + bmu4[nt];
                float lvv = acc[nt + 4][r] + blv4[nt];
                float eh = __expf(0.5f * lvv);
                kl_acc += 1.f + lvv - mu * mu - eh * eh;
                zn[nt][r] = mu + epr[nt * 4 + r] * eh;
            }
        {   // reissue eps
            const float* ep = eps_g + ((size_t)nxt * NK + rowbase) * NL;
#pragma unroll
            for (int nt = 0; nt < 4; ++nt)
#pragma unroll
                for (int r = 0; r < 4; ++r)
                    epr[nt * 4 + r] = ep[(4 * g + r) * NL + li + 16 * nt];
        }
        // ---- post-LN per row (shfl across li: 1,2,4,8) + logit ----
        float lg4[4];
#pragma unroll
        for (int r = 0; r < 4; ++r) {
            float zs = zn[0][r] + zn[1][r] + zn[2][r] + zn[3][r];
            zs += __shfl_xor(zs, 1); zs += __shfl_xor(zs, 2);
            zs += __shfl_xor(zs, 4); zs += __shfl_xor(zs, 8);
            float zm = zs * (1.f / 64.f);
            float zv = 0.f;
#pragma unroll
            for (int nt = 0; nt < 4; ++nt) { float d = zn[nt][r] - zm; zv += d * d; }
            zv += __shfl_xor(zv, 1); zv += __shfl_xor(zv, 2);
            zv += __shfl_xor(zv, 4); zv += __shfl_xor(zv, 8);
            float zi = rsqrtf(zv * (1.f / 64.f) + 1e-5f);
#pragma unroll
            for (int nt = 0; nt < 4; ++nt)
                zn[nt][r] = (zn[nt][r] - zm) * zi * pg4[nt] + pb4[nt];
            float lg = zn[0][r] * qk4[0] + zn[1][r] * qk4[1]
                     + zn[2][r] * qk4[2] + zn[3][r] * qk4[3];
            lg += __shfl_xor(lg, 1); lg += __shfl_xor(lg, 2);
            lg += __shfl_xor(lg, 4); lg += __shfl_xor(lg, 8);
            lg4[r] = lg * 0.125f + __logf(trl[r] + 1e-6f);
            if (li == 0) logit_l[st][rowbase + 4 * g + r] = lg4[r];
        }
        {   // reissue qk + trust
#pragma unroll
            for (int nt = 0; nt < 4; ++nt) qk4[nt] = qk_ws[(size_t)nxt * 64 + li + 16 * nt];
#pragma unroll
            for (int r = 0; r < 4; ++r) trl[r] = trust_mask[(size_t)nxt * NK + rowbase + 4 * g + r];
        }
        LBAR();   // b1: logits visible across the pair

        // ---- P3: softmax over 32 rows + per-wave zbar partial ----
        {
            float lv32 = logit_l[st][l & 31];
            float mx = lv32;
            mx = fmaxf(mx, __shfl_xor(mx, 1));  mx = fmaxf(mx, __shfl_xor(mx, 2));
            mx = fmaxf(mx, __shfl_xor(mx, 4));  mx = fmaxf(mx, __shfl_xor(mx, 8));
            mx = fmaxf(mx, __shfl_xor(mx, 16));
            float den = __expf(lv32 - mx);
            den += __shfl_xor(den, 1); den += __shfl_xor(den, 2);
            den += __shfl_xor(den, 4); den += __shfl_xor(den, 8);
            den += __shfl_xor(den, 16);
            float idn = 1.f / den;
            float att[4];
#pragma unroll
            for (int r = 0; r < 4; ++r) att[r] = __expf(lg4[r] - mx) * idn;
#pragma unroll
            for (int nt = 0; nt < 4; ++nt) {
                float zb = att[0] * zn[nt][0] + att[1] * zn[nt][1]
                         + att[2] * zn[nt][2] + att[3] * zn[nt][3];
                zb += __shfl_xor(zb, 16); zb += __shfl_xor(zb, 32);
                if (g == 0) zbar_l[st][p][li + 16 * nt] = zb;
            }
        }
        LBAR();   // b2: zbar partials visible

        // ---- P4: out cols 64p..64p+63 (lane l -> col 64p+l) ----
        {
            float o = 0.f;
#pragma unroll 8
            for (int c = 0; c < 64; ++c) {
                float zbc = zbar_l[st][0][c] + zbar_l[st][1][c];
                unsigned int u = WvoP[c * 64 + l];
                o += zbc * (p ? bfhi(u) : bflo(u));
            }
            out[(size_t)node * NH + 64 * p + l] = o + bvo_r;
        }
        node = nxt;
    }

    // ---- KL reduction ----
#pragma unroll
    for (int msk = 1; msk < 64; msk <<= 1) kl_acc += __shfl_xor(kl_acc, msk);
    if (l == 0) klw[w] = kl_acc;
    __syncthreads();
    if (t == 0) {
        float tot = klw[0] + klw[1] + klw[2] + klw[3];
        atomicAdd(out + (size_t)NB * NH, tot * (-0.5f * 0.001f / ((float)NB * NK)));
    }
}

extern "C" void kernel_launch(void* const* d_in, const int* in_sizes, int n_in,
                              void* d_out, int out_size, void* d_ws, size_t ws_size,
                              hipStream_t stream) {
    const float* self_feat     = (const float*)d_in[0];
    const float* neighbor_feat = (const float*)d_in[1];
    const float* trust_mask    = (const float*)d_in[2];
    const float* eps           = (const float*)d_in[3];
    const float* pre_g  = (const float*)d_in[4];
    const float* pre_b  = (const float*)d_in[5];
    const float* W_mu   = (const float*)d_in[6];
    const float* b_mu   = (const float*)d_in[7];
    const float* W_lv   = (const float*)d_in[8];
    const float* b_lv   = (const float*)d_in[9];
    const float* post_g = (const float*)d_in[10];
    const float* post_b = (const float*)d_in[11];
    const float* W_q    = (const float*)d_in[12];
    const float* b_q    = (const float*)d_in[13];
    const float* W_k    = (const float*)d_in[14];
    const float* W_v    = (const float*)d_in[16];
    const float* b_v    = (const float*)d_in[17];
    const float* W_o    = (const float*)d_in[18];
    const float* b_o    = (const float*)d_in[19];
    float* out = (float*)d_out;

    // ws: qk f32 [NB,64] (12.8MB) | Wvo f32 [64,128] | bvo f32 [128]
    float* qk_ws  = (float*)d_ws;
    float* wvo_ws = qk_ws + (size_t)NB * 64;
    float* bvo_ws = wvo_ws + 64 * 128;

    hipLaunchKernelGGL(kl_zero_kernel, dim3(1), dim3(64), 0, stream, out);
    hipLaunchKernelGGL(wvo_kernel, dim3(1), dim3(256), 0, stream, W_v, W_o, b_v, b_o, wvo_ws, bvo_ws);
    hipLaunchKernelGGL(qk_kernel, dim3((NB + 31) / 32), dim3(256), 0, stream,
                       self_feat, W_q, b_q, W_k, qk_ws);
    hipLaunchKernelGGL(fz13_kernel, dim3(NB / 8), dim3(256), 0, stream,
                       neighbor_feat, trust_mask, eps, pre_g, pre_b,
                       W_mu, b_mu, W_lv, b_lv, post_g, post_b,
                       qk_ws, wvo_ws, bvo_ws, out);
}

// Round 14
// 546.976 us; speedup vs baseline: 1.0096x; 1.0096x over previous
//
#include <hip/hip_runtime.h>
#include <hip/hip_bf16.h>

typedef float f32x4 __attribute__((ext_vector_type(4)));
typedef short bf16x8 __attribute__((ext_vector_type(8)));

#define NB 50000
#define NK 32
#define NH 128
#define NL 64

// LDS-only barrier: waits LDS ops, leaves global (vmcnt) prefetch in flight.
#define LBAR() do { asm volatile("s_waitcnt lgkmcnt(0)" ::: "memory"); \
                    __builtin_amdgcn_s_barrier(); \
                    asm volatile("" ::: "memory"); } while (0)

static __device__ __forceinline__ unsigned short f2bf(float f) {
    unsigned int u = __float_as_uint(f);
    u += 0x7fffu + ((u >> 16) & 1u);
    return (unsigned short)(u >> 16);
}
static __device__ __forceinline__ float bf2f(unsigned short u) {
    return __uint_as_float(((unsigned int)u) << 16);
}
static __device__ __forceinline__ float bflo(unsigned int u) { return __uint_as_float(u << 16); }
static __device__ __forceinline__ float bfhi(unsigned int u) { return __uint_as_float(u & 0xffff0000u); }

__global__ void kl_zero_kernel(float* out) {
    if (threadIdx.x == 0 && blockIdx.x == 0) out[(size_t)NB * NH] = 0.0f;
}

// ---------------- K0: Wvo = Wv@Wo (f32, ws), bvo = b_v@Wo + b_o ----------------
__global__ void __launch_bounds__(256) wvo_kernel(const float* __restrict__ W_v,
                                                  const float* __restrict__ W_o,
                                                  const float* __restrict__ b_v,
                                                  const float* __restrict__ b_o,
                                                  float* __restrict__ wvo_ws,
                                                  float* __restrict__ bvo_ws)
{
    const int t = threadIdx.x;
    for (int e = t; e < 64 * 128; e += 256) {
        int d = e >> 7, h = e & 127;
        float s = 0.f;
#pragma unroll 8
        for (int c = 0; c < 64; ++c) s += W_v[d * 64 + c] * W_o[c * 128 + h];
        wvo_ws[e] = s;
    }
    if (t < 128) {
        float s = b_o[t];
#pragma unroll 8
        for (int c = 0; c < 64; ++c) s += b_v[c] * W_o[c * 128 + t];
        bvo_ws[t] = s;
    }
}

// ---------------- K1: qk = (self@Wq + b_q) @ Wk^T   (f32 out to ws) ----------------
__global__ void __launch_bounds__(256) qk_kernel(const float* __restrict__ self_feat,
                                                 const float* __restrict__ W_q,
                                                 const float* __restrict__ b_q,
                                                 const float* __restrict__ W_k,
                                                 float* __restrict__ qk_ws)
{
    __shared__ __align__(16) unsigned short A[32 * 128];
    __shared__ __align__(16) unsigned short ZQ[32 * 64];
    const int t = threadIdx.x, w = t >> 6, l = t & 63, g = l >> 4, li = l & 15;

    bf16x8 Bq[4];
#pragma unroll
    for (int s = 0; s < 4; ++s) {
        int k0 = 32 * s + 8 * g, c = li + 16 * w;
        bf16x8 f;
#pragma unroll
        for (int j = 0; j < 8; ++j) f[j] = (short)f2bf(W_q[(k0 + j) * 64 + c]);
        Bq[s] = f;
    }
    bf16x8 Bk[2];
#pragma unroll
    for (int s = 0; s < 2; ++s) {
        int k0 = 32 * s + 8 * g, d = li + 16 * w;
        bf16x8 f;
#pragma unroll
        for (int j = 0; j < 8; ++j) f[j] = (short)f2bf(W_k[d * 64 + k0 + j]);
        Bk[s] = f;
    }
    const float bq = b_q[li + 16 * w];
    const int n0 = blockIdx.x * 32;

    {
        int row = t >> 3, c0 = (t & 7) * 16;
        float x[16];
        if (n0 + row < NB) {
            const float* src = self_feat + (size_t)(n0 + row) * NH + c0;
#pragma unroll
            for (int i = 0; i < 4; ++i) {
                float4 v4 = ((const float4*)src)[i];
                x[4 * i] = v4.x; x[4 * i + 1] = v4.y; x[4 * i + 2] = v4.z; x[4 * i + 3] = v4.w;
            }
        } else {
#pragma unroll
            for (int i = 0; i < 16; ++i) x[i] = 0.f;
        }
        alignas(16) unsigned short yb[16];
#pragma unroll
        for (int i = 0; i < 16; ++i) yb[i] = f2bf(x[i]);
        int boff = row * 256 + c0 * 2;
        *(int4*)((char*)A + ((boff) ^ ((row & 7) << 4))) = *(int4*)&yb[0];
        *(int4*)((char*)A + ((boff + 16) ^ ((row & 7) << 4))) = *(int4*)&yb[8];
    }
    __syncthreads();

    const f32x4 zero4 = {0.f, 0.f, 0.f, 0.f};
    f32x4 acc[2] = {zero4, zero4};
#pragma unroll
    for (int s = 0; s < 4; ++s) {
        bf16x8 A0 = *(const bf16x8*)((const char*)A + ((li * 256 + s * 64 + g * 16) ^ ((li & 7) << 4)));
        bf16x8 A1 = *(const bf16x8*)((const char*)A + (((16 + li) * 256 + s * 64 + g * 16) ^ ((li & 7) << 4)));
        acc[0] = __builtin_amdgcn_mfma_f32_16x16x32_bf16(A0, Bq[s], acc[0], 0, 0, 0);
        acc[1] = __builtin_amdgcn_mfma_f32_16x16x32_bf16(A1, Bq[s], acc[1], 0, 0, 0);
    }
#pragma unroll
    for (int mt = 0; mt < 2; ++mt)
#pragma unroll
        for (int r = 0; r < 4; ++r) {
            int row = 16 * mt + 4 * g + r, c = li + 16 * w;
            *(unsigned short*)((char*)ZQ + ((row * 128 + c * 2) ^ ((row & 7) << 4))) = f2bf(acc[mt][r] + bq);
        }
    __syncthreads();

    f32x4 acc2[2] = {zero4, zero4};
#pragma unroll
    for (int s = 0; s < 2; ++s) {
        bf16x8 A0 = *(const bf16x8*)((const char*)ZQ + ((li * 128 + s * 64 + g * 16) ^ ((li & 7) << 4)));
        bf16x8 A1 = *(const bf16x8*)((const char*)ZQ + (((16 + li) * 128 + s * 64 + g * 16) ^ (((16 + li) & 7) << 4)));
        acc2[0] = __builtin_amdgcn_mfma_f32_16x16x32_bf16(A0, Bk[s], acc2[0], 0, 0, 0);
        acc2[1] = __builtin_amdgcn_mfma_f32_16x16x32_bf16(A1, Bk[s], acc2[1], 0, 0, 0);
    }
#pragma unroll
    for (int mt = 0; mt < 2; ++mt)
#pragma unroll
        for (int r = 0; r < 4; ++r) {
            int row = 16 * mt + 4 * g + r;
            if (n0 + row < NB)
                qk_ws[(size_t)(n0 + row) * 64 + li + 16 * w] = acc2[mt][r];
        }
}

// ---- K2: fused main — 512 thr = 4 wave-pair streams sharing one weight-LDS copy ----
// Wave w (0..7): stream st=w>>1 (0..3), pair-half p=w&1 (rows 16p..16p+15).
__global__ void __launch_bounds__(512) fz14_kernel(
    const float* __restrict__ neighbor_feat, const float* __restrict__ trust_mask,
    const float* __restrict__ eps_g,
    const float* __restrict__ pre_g, const float* __restrict__ pre_b,
    const float* __restrict__ W_mu, const float* __restrict__ b_mu,
    const float* __restrict__ W_lv, const float* __restrict__ b_lv,
    const float* __restrict__ post_g, const float* __restrict__ post_b,
    const float* __restrict__ qk_ws, const float* __restrict__ wvo_ws,
    const float* __restrict__ bvo_ws,
    float* __restrict__ out)
{
    __shared__ uint4 WmlB[8 * 4 * 64];        // 32KB shared by all 8 waves
    __shared__ unsigned int WvoP[64 * 64];    // 16KB
    __shared__ float2 s_pgb[128];             // 1KB
    __shared__ float logit_l[4][32];          // per-stream logits
    __shared__ float zbar_l[4][2][64];        // per-stream per-half zbar partials (2KB)
    __shared__ float klw[8];

    const int t = threadIdx.x, w = t >> 6, l = t & 63, g = l >> 4, li = l & 15;
    const int st = w >> 1, p = w & 1;

    if (t < 128) s_pgb[t] = make_float2(pre_g[t], pre_b[t]);
    for (int e = t; e < 2048; e += 512) {   // WmlB
        int nt = e >> 8, s = (e >> 6) & 3, ln = e & 63;
        const float* src = (nt < 4) ? W_mu : W_lv;
        int gg = ln >> 4, ll = ln & 15, c = ll + 16 * (nt & 3);
        unsigned int pk[4];
#pragma unroll
        for (int jp = 0; jp < 4; ++jp) {
            int k = 32 * s + 8 * gg + 2 * jp;
            pk[jp] = (unsigned)f2bf(src[k * 64 + c]) | ((unsigned)f2bf(src[(k + 1) * 64 + c]) << 16);
        }
        WmlB[e] = make_uint4(pk[0], pk[1], pk[2], pk[3]);
    }
    for (int e = t; e < 4096; e += 512) {   // WvoP
        int c = e >> 6, h = e & 63;
        WvoP[e] = (unsigned)f2bf(wvo_ws[c * 128 + h]) | ((unsigned)f2bf(wvo_ws[c * 128 + h + 64]) << 16);
    }
    float bmu4[4], blv4[4], pg4[4], pb4[4];
#pragma unroll
    for (int nt = 0; nt < 4; ++nt) {
        int c = li + 16 * nt;
        bmu4[nt] = b_mu[c]; blv4[nt] = b_lv[c]; pg4[nt] = post_g[c]; pb4[nt] = post_b[c];
    }
    const float bvo_r = bvo_ws[64 * p + l];
    __syncthreads();

    int node = blockIdx.x * 16 + 4 * st;   // stream st handles nodes node..node+3
    const int rowbase = 16 * p;

    f32x4 xr[4][2];      // row 16p+li, cols 32s+8g+4h+{0..3}
    float epr[16];       // eps[row 16p+4g+r][col li+16nt]
    float qk4[4], trl[4];
    {   // prologue prefetch
        const float* src = neighbor_feat + ((size_t)node * NK + rowbase + li) * NH + 8 * g;
#pragma unroll
        for (int s = 0; s < 4; ++s)
#pragma unroll
            for (int h = 0; h < 2; ++h)
                xr[s][h] = *(const f32x4*)(src + 32 * s + 4 * h);
        const float* ep = eps_g + ((size_t)node * NK + rowbase) * NL;
#pragma unroll
        for (int nt = 0; nt < 4; ++nt)
#pragma unroll
            for (int r = 0; r < 4; ++r)
                epr[nt * 4 + r] = ep[(4 * g + r) * NL + li + 16 * nt];
#pragma unroll
        for (int nt = 0; nt < 4; ++nt) qk4[nt] = qk_ws[(size_t)node * 64 + li + 16 * nt];
#pragma unroll
        for (int r = 0; r < 4; ++r) trl[r] = trust_mask[(size_t)node * NK + rowbase + 4 * g + r];
    }

    float kl_acc = 0.f;
    const f32x4 zero4 = {0.f, 0.f, 0.f, 0.f};

#pragma unroll 1
    for (int i = 0; i < 4; ++i) {
        const int nxt = (i < 3) ? node + 1 : node;

        // ---- P0: pre-LN in registers (row stats across g via shfl 16/32) ----
        float s1 = 0.f;
#pragma unroll
        for (int s = 0; s < 4; ++s)
#pragma unroll
            for (int h = 0; h < 2; ++h) {
                f32x4 v = xr[s][h];
                s1 += v[0] + v[1] + v[2] + v[3];
            }
        s1 += __shfl_xor(s1, 16); s1 += __shfl_xor(s1, 32);
        float mean = s1 * (1.f / 128.f);
        float s2 = 0.f;
#pragma unroll
        for (int s = 0; s < 4; ++s)
#pragma unroll
            for (int h = 0; h < 2; ++h)
#pragma unroll
                for (int c = 0; c < 4; ++c) { float d = xr[s][h][c] - mean; s2 += d * d; }
        s2 += __shfl_xor(s2, 16); s2 += __shfl_xor(s2, 32);
        float inv = rsqrtf(s2 * (1.f / 128.f) + 1e-5f);
        bf16x8 a[4];
#pragma unroll
        for (int s = 0; s < 4; ++s) {
            const float2* gbp = &s_pgb[32 * s + 8 * g];
#pragma unroll
            for (int h = 0; h < 2; ++h)
#pragma unroll
                for (int c = 0; c < 4; ++c) {
                    int j = 4 * h + c;
                    float2 gb = gbp[j];
                    a[s][j] = (short)f2bf((xr[s][h][c] - mean) * inv * gb.x + gb.y);
                }
        }
        {   // reissue nbr for next node
            const float* src = neighbor_feat + ((size_t)nxt * NK + rowbase + li) * NH + 8 * g;
#pragma unroll
            for (int s = 0; s < 4; ++s)
#pragma unroll
                for (int h = 0; h < 2; ++h)
                    xr[s][h] = *(const f32x4*)(src + 32 * s + 4 * h);
        }

        // ---- P1: GEMM1: 16 rows x 128 cols [mu|lv], all in this wave ----
        f32x4 acc[8];
#pragma unroll
        for (int nt = 0; nt < 8; ++nt) acc[nt] = zero4;
#pragma unroll
        for (int s = 0; s < 4; ++s)
#pragma unroll
            for (int nt = 0; nt < 8; ++nt) {
                bf16x8 fb = *(const bf16x8*)&WmlB[(nt * 4 + s) * 64 + l];
                acc[nt] = __builtin_amdgcn_mfma_f32_16x16x32_bf16(a[s], fb, acc[nt], 0, 0, 0);
            }

        // ---- P2: reparam + KL (lane-local) ----
        float zn[4][4];
#pragma unroll
        for (int nt = 0; nt < 4; ++nt)
#pragma unroll
            for (int r = 0; r < 4; ++r) {
                float mu = acc[nt][r] + bmu4[nt];
                float lvv = acc[nt + 4][r] + blv4[nt];
                float eh = __expf(0.5f * lvv);
                kl_acc += 1.f + lvv - mu * mu - eh * eh;
                zn[nt][r] = mu + epr[nt * 4 + r] * eh;
            }
        {   // reissue eps
            const float* ep = eps_g + ((size_t)nxt * NK + rowbase) * NL;
#pragma unroll
            for (int nt = 0; nt < 4; ++nt)
#pragma unroll
                for (int r = 0; r < 4; ++r)
                    epr[nt * 4 + r] = ep[(4 * g + r) * NL + li + 16 * nt];
        }
        // ---- post-LN per row (shfl across li: 1,2,4,8) + logit ----
        float lg4[4];
#pragma unroll
        for (int r = 0; r < 4; ++r) {
            float zs = zn[0][r] + zn[1][r] + zn[2][r] + zn[3][r];
            zs += __shfl_xor(zs, 1); zs += __shfl_xor(zs, 2);
            zs += __shfl_xor(zs, 4); zs += __shfl_xor(zs, 8);
            float zm = zs * (1.f / 64.f);
            float zv = 0.f;
#pragma unroll
            for (int nt = 0; nt < 4; ++nt) { float d = zn[nt][r] - zm; zv += d * d; }
            zv += __shfl_xor(zv, 1); zv += __shfl_xor(zv, 2);
            zv += __shfl_xor(zv, 4); zv += __shfl_xor(zv, 8);
            float zi = rsqrtf(zv * (1.f / 64.f) + 1e-5f);
#pragma unroll
            for (int nt = 0; nt < 4; ++nt)
                zn[nt][r] = (zn[nt][r] - zm) * zi * pg4[nt] + pb4[nt];
            float lg = zn[0][r] * qk4[0] + zn[1][r] * qk4[1]
                     + zn[2][r] * qk4[2] + zn[3][r] * qk4[3];
            lg += __shfl_xor(lg, 1); lg += __shfl_xor(lg, 2);
            lg += __shfl_xor(lg, 4); lg += __shfl_xor(lg, 8);
            lg4[r] = lg * 0.125f + __logf(trl[r] + 1e-6f);
            if (li == 0) logit_l[st][rowbase + 4 * g + r] = lg4[r];
        }
        {   // reissue qk + trust
#pragma unroll
            for (int nt = 0; nt < 4; ++nt) qk4[nt] = qk_ws[(size_t)nxt * 64 + li + 16 * nt];
#pragma unroll
            for (int r = 0; r < 4; ++r) trl[r] = trust_mask[(size_t)nxt * NK + rowbase + 4 * g + r];
        }
        LBAR();   // b1: logits visible across the pair

        // ---- P3: softmax over 32 rows + per-wave zbar partial ----
        {
            float lv32 = logit_l[st][l & 31];
            float mx = lv32;
            mx = fmaxf(mx, __shfl_xor(mx, 1));  mx = fmaxf(mx, __shfl_xor(mx, 2));
            mx = fmaxf(mx, __shfl_xor(mx, 4));  mx = fmaxf(mx, __shfl_xor(mx, 8));
            mx = fmaxf(mx, __shfl_xor(mx, 16));
            float den = __expf(lv32 - mx);
            den += __shfl_xor(den, 1); den += __shfl_xor(den, 2);
            den += __shfl_xor(den, 4); den += __shfl_xor(den, 8);
            den += __shfl_xor(den, 16);
            float idn = 1.f / den;
            float att[4];
#pragma unroll
            for (int r = 0; r < 4; ++r) att[r] = __expf(lg4[r] - mx) * idn;
#pragma unroll
            for (int nt = 0; nt < 4; ++nt) {
                float zb = att[0] * zn[nt][0] + att[1] * zn[nt][1]
                         + att[2] * zn[nt][2] + att[3] * zn[nt][3];
                zb += __shfl_xor(zb, 16); zb += __shfl_xor(zb, 32);
                if (g == 0) zbar_l[st][p][li + 16 * nt] = zb;
            }
        }
        LBAR();   // b2: zbar partials visible

        // ---- P4: out cols 64p..64p+63 (lane l -> col 64p+l) ----
        {
            float o = 0.f;
#pragma unroll 8
            for (int c = 0; c < 64; ++c) {
                float zbc = zbar_l[st][0][c] + zbar_l[st][1][c];
                unsigned int u = WvoP[c * 64 + l];
                o += zbc * (p ? bfhi(u) : bflo(u));
            }
            out[(size_t)node * NH + 64 * p + l] = o + bvo_r;
        }
        node = nxt;
    }

    // ---- KL reduction ----
#pragma unroll
    for (int msk = 1; msk < 64; msk <<= 1) kl_acc += __shfl_xor(kl_acc, msk);
    if (l == 0) klw[w] = kl_acc;
    __syncthreads();
    if (t == 0) {
        float tot = klw[0] + klw[1] + klw[2] + klw[3]
                  + klw[4] + klw[5] + klw[6] + klw[7];
        atomicAdd(out + (size_t)NB * NH, tot * (-0.5f * 0.001f / ((float)NB * NK)));
    }
}

extern "C" void kernel_launch(void* const* d_in, const int* in_sizes, int n_in,
                              void* d_out, int out_size, void* d_ws, size_t ws_size,
                              hipStream_t stream) {
    const float* self_feat     = (const float*)d_in[0];
    const float* neighbor_feat = (const float*)d_in[1];
    const float* trust_mask    = (const float*)d_in[2];
    const float* eps           = (const float*)d_in[3];
    const float* pre_g  = (const float*)d_in[4];
    const float* pre_b  = (const float*)d_in[5];
    const float* W_mu   = (const float*)d_in[6];
    const float* b_mu   = (const float*)d_in[7];
    const float* W_lv   = (const float*)d_in[8];
    const float* b_lv   = (const float*)d_in[9];
    const float* post_g = (const float*)d_in[10];
    const float* post_b = (const float*)d_in[11];
    const float* W_q    = (const float*)d_in[12];
    const float* b_q    = (const float*)d_in[13];
    const float* W_k    = (const float*)d_in[14];
    const float* W_v    = (const float*)d_in[16];
    const float* b_v    = (const float*)d_in[17];
    const float* W_o    = (const float*)d_in[18];
    const float* b_o    = (const float*)d_in[19];
    float* out = (float*)d_out;

    // ws: qk f32 [NB,64] (12.8MB) | Wvo f32 [64,128] | bvo f32 [128]
    float* qk_ws  = (float*)d_ws;
    float* wvo_ws = qk_ws + (size_t)NB * 64;
    float* bvo_ws = wvo_ws + 64 * 128;

    hipLaunchKernelGGL(kl_zero_kernel, dim3(1), dim3(64), 0, stream, out);
    hipLaunchKernelGGL(wvo_kernel, dim3(1), dim3(256), 0, stream, W_v, W_o, b_v, b_o, wvo_ws, bvo_ws);
    hipLaunchKernelGGL(qk_kernel, dim3((NB + 31) / 32), dim3(256), 0, stream,
                       self_feat, W_q, b_q, W_k, qk_ws);
    hipLaunchKernelGGL(fz14_kernel, dim3(NB / 16), dim3(512), 0, stream,
                       neighbor_feat, trust_mask, eps, pre_g, pre_b,
                       W_mu, b_mu, W_lv, b_lv, post_g, post_b,
                       qk_ws, wvo_ws, bvo_ws, out);
}